// Round 1
// baseline (680.018 us; speedup 1.0000x reference)
//
#include <hip/hip_runtime.h>
#include <math.h>

#ifndef INT_MAX
#define INT_MAX 0x7fffffff
#endif

// ---------------------------------------------------------------------------
// MultiScaleROIEmbedder: exploit linearity of proj/bilinear/mean:
//   tok_s[n] = (1/36) * ( W_s @ G_s[n] + cnt_n * b_s + P_s[n] )
// G = weighted raw-feature sum over the ROI's dense (row,col) weight grid,
// P = separable positional-encoding sum (analytic sincos), then GEMM + MLP.
// ---------------------------------------------------------------------------

__device__ __forceinline__ float gelu_exact(float x) {
    return 0.5f * x * (1.0f + erff(x * 0.70710678118654752f));
}

// ---- Kernel 0: transpose the projection / MLP weights for coalesced reads --
__global__ __launch_bounds__(256)
void build_wt_kernel(const float* __restrict__ W3, const float* __restrict__ W4,
                     const float* __restrict__ W5, const float* __restrict__ W1,
                     const float* __restrict__ W2,
                     float* __restrict__ WT, float* __restrict__ W1T,
                     float* __restrict__ W2T)
{
    int k = blockIdx.x;      // 0..4095
    int d = threadIdx.x;     // 0..255
    if (k < 512)       WT[(size_t)k * 256 + d]          = W3[(size_t)d * 512  + k];
    else if (k < 1536) WT[(size_t)k * 256 + d]          = W4[(size_t)d * 1024 + (k - 512)];
    else if (k < 3584) WT[(size_t)k * 256 + d]          = W5[(size_t)d * 2048 + (k - 1536)];
    else if (k < 3840) W1T[(size_t)(k - 3584) * 256 + d] = W1[(size_t)d * 256 + (k - 3584)];
    else               W2T[(size_t)(k - 3840) * 256 + d] = W2[(size_t)d * 256 + (k - 3840)];
}

// ---- Kernel 1: per (ROI, scale) weighted feature gather + pos-enc sum ------
__global__ __launch_bounds__(256)
void roi_gather_kernel(const float* __restrict__ p3, const float* __restrict__ p4,
                       const float* __restrict__ p5,
                       const float* __restrict__ boxes,
                       const float* __restrict__ b3, const float* __restrict__ b4,
                       const float* __restrict__ b5,
                       const int* __restrict__ iw_p, const int* __restrict__ ih_p,
                       float* __restrict__ G, float* __restrict__ P,
                       int K)
{
    const int n   = blockIdx.x;   // token index (b*K + k)
    const int s   = blockIdx.y;   // scale 0/1/2
    const int tid = threadIdx.x;

    int C, H, W, koff;
    const float* feat;
    const float* bp;
    if (s == 0)      { C = 512;  H = 128; W = 128; koff = 0;    feat = p3; bp = b3; }
    else if (s == 1) { C = 1024; H = 64;  W = 64;  koff = 512;  feat = p4; bp = b4; }
    else             { C = 2048; H = 32;  W = 32;  koff = 1536; feat = p5; bp = b5; }
    const int HW = H * W;
    const int b  = n / K;

    __shared__ float wy[32];
    __shared__ float wx[48];
    __shared__ int   sh_r0, sh_rs, sh_x0, sh_nc;
    __shared__ float sh_syc, sh_sxc;

    if (tid < 32)                 wy[tid]      = 0.0f;
    if (tid >= 32 && tid < 80)    wx[tid - 32] = 0.0f;
    __syncthreads();

    const float scale = fminf((float)W / ((float)(*iw_p) + 1e-6f),
                              (float)H / ((float)(*ih_p) + 1e-6f));

    if (tid == 0) {
        // y axis: dense row weights (validity folded in)
        float c1 = boxes[(size_t)n * 4 + 1] * scale - 0.5f;
        float c2 = boxes[(size_t)n * 4 + 3] * scale - 0.5f;
        float bs = (c2 - c1) / 3.0f;
        int   yls[6], yhs[6], vv[6];
        float lys[6];
        int r0 = INT_MAX; float cnt = 0.0f;
        #pragma unroll
        for (int i = 0; i < 6; ++i) {
            float off = 0.25f + 0.5f * (float)i;
            float ys  = c1 + bs * off;
            int v = (ys >= -1.0f) && (ys <= (float)H);
            float yc = fmaxf(ys, 0.0f);
            int yl = (int)floorf(yc); if (yl > H - 1) yl = H - 1;
            int yh = yl + 1;          if (yh > H - 1) yh = H - 1;
            float ly = yc - (float)yl;
            yls[i] = yl; yhs[i] = yh; lys[i] = ly; vv[i] = v;
            if (v) { r0 = min(r0, yl); cnt += 1.0f; }
        }
        if (r0 == INT_MAX) r0 = 0;
        int rmax = 0;
        #pragma unroll
        for (int i = 0; i < 6; ++i) if (vv[i]) {
            int a = min(yls[i] - r0, 31);
            int h = min(yhs[i] - r0, 31);
            wy[a] += 1.0f - lys[i];
            wy[h] += lys[i];
            rmax = max(rmax, h);
        }
        sh_r0 = r0; sh_rs = rmax + 1; sh_syc = cnt;
    }
    if (tid == 1) {
        // x axis: dense col weights on a 16-float (64B) aligned window
        float c1 = boxes[(size_t)n * 4 + 0] * scale - 0.5f;
        float c2 = boxes[(size_t)n * 4 + 2] * scale - 0.5f;
        float bs = (c2 - c1) / 3.0f;
        int   xls[6], xhs[6], vv[6];
        float lxs[6];
        int x0r = INT_MAX; float cnt = 0.0f;
        #pragma unroll
        for (int i = 0; i < 6; ++i) {
            float off = 0.25f + 0.5f * (float)i;
            float xs  = c1 + bs * off;
            int v = (xs >= -1.0f) && (xs <= (float)W);
            float xc = fmaxf(xs, 0.0f);
            int xl = (int)floorf(xc); if (xl > W - 1) xl = W - 1;
            int xh = xl + 1;          if (xh > W - 1) xh = W - 1;
            float lx = xc - (float)xl;
            xls[i] = xl; xhs[i] = xh; lxs[i] = lx; vv[i] = v;
            if (v) { x0r = min(x0r, xl); cnt += 1.0f; }
        }
        if (x0r == INT_MAX) x0r = 0;
        int x0 = x0r & ~15;
        int imax = 0;
        #pragma unroll
        for (int i = 0; i < 6; ++i) if (vv[i]) {
            int a = min(xls[i] - x0, 47);
            int h = min(xhs[i] - x0, 47);
            wx[a] += 1.0f - lxs[i];
            wx[h] += lxs[i];
            imax = max(imax, h);
        }
        int nc = imax / 16 + 1;
        int ncmax = (W - x0) >> 4;
        nc = min(nc, ncmax);
        sh_x0 = x0; sh_nc = max(nc, 1); sh_sxc = cnt;
    }
    __syncthreads();

    const int lane = tid & 63;
    const int wv   = tid >> 6;          // wave 0..3
    const int lx   = lane & 15;         // x slot within 64B line
    const int cq   = lane >> 4;         // channel quad within wave
    const int r0 = sh_r0, rs = sh_rs, x0 = sh_x0, nc = sh_nc;

    const size_t bbase = (size_t)b * (size_t)C * (size_t)HW;
    const int iters = C >> 4;           // 16 channels per block iteration

    for (int it = 0; it < iters; ++it) {
        int c = (it << 4) + (wv << 2) + cq;
        const float* fp = feat + bbase + (size_t)c * HW + x0 + lx;
        float acc = 0.0f;
        for (int ch = 0; ch < nc; ++ch) {
            float wxl = wx[(ch << 4) + lx];
            const float* fr = fp + (ch << 4) + r0 * W;
            float ra = 0.0f;
            for (int r = 0; r < rs; ++r) {
                ra = fmaf(wy[r], fr[0], ra);
                fr += W;
            }
            acc = fmaf(wxl, ra, acc);
        }
        // reduce 16 x-lanes -> channel value
        #pragma unroll
        for (int o = 8; o; o >>= 1) acc += __shfl_xor(acc, o, 16);
        if (lx == 0) G[(size_t)n * 3584 + koff + c] = acc * (1.0f / 36.0f);
    }

    // positional encoding + bias term, folded with count and 1/36
    {
        const int d = tid;
        const float syc = sh_syc, sxc = sh_sxc;
        float val;
        if (d < 128) {
            int   t     = d >> 2;
            float invf  = expf(-(float)t * (logf(10000.0f) / 32.0f));
            float istep = 1.0f / (float)(H - 1);
            float sum = 0.0f;
            for (int r = 0; r < rs; ++r) {
                float w = wy[r];
                float ang = (float)(r0 + r) * istep * invf;
                float sn, cs; sincosf(ang, &sn, &cs);
                sum = fmaf(w, (d & 1) ? cs : sn, sum);
            }
            val = sxc * sum;
        } else {
            int   d2    = d - 128;
            int   t     = d2 >> 2;
            float invf  = expf(-(float)t * (logf(10000.0f) / 32.0f));
            float istep = 1.0f / (float)(W - 1);
            float sum = 0.0f;
            int nx = nc << 4;
            for (int j = 0; j < nx; ++j) {
                float w = wx[j];
                if (w != 0.0f) {
                    float ang = (float)(x0 + j) * istep * invf;
                    float sn, cs; sincosf(ang, &sn, &cs);
                    sum = fmaf(w, (d & 1) ? cs : sn, sum);
                }
            }
            val = syc * sum;
        }
        float cnt = syc * sxc;
        P[((size_t)n * 3 + s) * 256 + d] = (val + cnt * bp[d]) * (1.0f / 36.0f);
    }
}

// ---- Kernel 2: projection GEMM (N x 3584) @ (3584 x 256), K-split by 7 -----
__global__ __launch_bounds__(256)
void proj_gemm_kernel(const float* __restrict__ G, const float* __restrict__ WT,
                      float* __restrict__ part, int N)
{
    const int n0  = blockIdx.x * 8;
    const int kc  = blockIdx.y;          // 0..6, 512 K each
    const int tid = threadIdx.x;         // output dim d

    __shared__ float gl[8][128];
    float acc[8];
    #pragma unroll
    for (int t = 0; t < 8; ++t) acc[t] = 0.0f;

    const int kbase = kc * 512;
    const int lt  = tid >> 5;            // token 0..7 for staging
    const int lc  = (tid & 31) * 4;      // col 0..124

    for (int sub = 0; sub < 4; ++sub) {
        const float4 g4 = *(const float4*)&G[(size_t)(n0 + lt) * 3584 + kbase + sub * 128 + lc];
        *(float4*)&gl[lt][lc] = g4;
        __syncthreads();
        const float* wtp = &WT[(size_t)(kbase + sub * 128) * 256 + tid];
        #pragma unroll 4
        for (int k = 0; k < 128; ++k) {
            float w = wtp[(size_t)k * 256];
            #pragma unroll
            for (int t = 0; t < 8; ++t) acc[t] = fmaf(gl[t][k], w, acc[t]);
        }
        __syncthreads();
    }
    #pragma unroll
    for (int t = 0; t < 8; ++t)
        part[((size_t)kc * N + n0 + t) * 256 + tid] = acc[t];
}

// ---- Kernel 3: reduce partials + P, LayerNorm, Linear-GELU-Linear ----------
__global__ __launch_bounds__(256)
void mlp_kernel(const float* __restrict__ part, const float* __restrict__ P,
                const float* __restrict__ lng, const float* __restrict__ lnb,
                const float* __restrict__ W1T, const float* __restrict__ b1,
                const float* __restrict__ W2T, const float* __restrict__ b2,
                float* __restrict__ out, int N)
{
    const int n0  = blockIdx.x * 8;
    const int tid = threadIdx.x;         // dim d

    __shared__ float tokl[8][257];
    __shared__ float hl[8][257];
    __shared__ float mval[8], rstd[8];

    #pragma unroll
    for (int t = 0; t < 8; ++t) {
        const int n = n0 + t;
        float v = 0.0f;
        #pragma unroll
        for (int c = 0; c < 7; ++c) v += part[((size_t)c * N + n) * 256 + tid];
        #pragma unroll
        for (int s = 0; s < 3; ++s) v += P[((size_t)n * 3 + s) * 256 + tid];
        tokl[t][tid] = v;
    }
    __syncthreads();

    const int wv = tid >> 6, lane = tid & 63;
    for (int t = wv; t < 8; t += 4) {
        float x0 = tokl[t][lane], x1 = tokl[t][lane + 64];
        float x2 = tokl[t][lane + 128], x3 = tokl[t][lane + 192];
        float sm = x0 + x1 + x2 + x3;
        float sq = x0 * x0 + x1 * x1 + x2 * x2 + x3 * x3;
        #pragma unroll
        for (int o = 32; o; o >>= 1) { sm += __shfl_xor(sm, o); sq += __shfl_xor(sq, o); }
        if (lane == 0) {
            float m   = sm * (1.0f / 256.0f);
            float var = sq * (1.0f / 256.0f) - m * m;
            mval[t] = m;
            rstd[t] = rsqrtf(var + 1e-5f);
        }
    }
    __syncthreads();

    const float g = lng[tid], be = lnb[tid];
    #pragma unroll
    for (int t = 0; t < 8; ++t)
        hl[t][tid] = (tokl[t][tid] - mval[t]) * rstd[t] * g + be;
    __syncthreads();

    float acc[8];
    const float bb1 = b1[tid];
    #pragma unroll
    for (int t = 0; t < 8; ++t) acc[t] = bb1;
    for (int k = 0; k < 256; ++k) {
        float w = W1T[(size_t)k * 256 + tid];
        #pragma unroll
        for (int t = 0; t < 8; ++t) acc[t] = fmaf(hl[t][k], w, acc[t]);
    }
    __syncthreads();   // all reads of hl done before tokl reuse is irrelevant; keep ordering safe
    #pragma unroll
    for (int t = 0; t < 8; ++t) tokl[t][tid] = gelu_exact(acc[t]);
    __syncthreads();

    const float bb2 = b2[tid];
    #pragma unroll
    for (int t = 0; t < 8; ++t) acc[t] = bb2;
    for (int k = 0; k < 256; ++k) {
        float w = W2T[(size_t)k * 256 + tid];
        #pragma unroll
        for (int t = 0; t < 8; ++t) acc[t] = fmaf(tokl[t][k], w, acc[t]);
    }
    #pragma unroll
    for (int t = 0; t < 8; ++t)
        out[(size_t)(n0 + t) * 256 + tid] = acc[t];
}

// ---------------------------------------------------------------------------
extern "C" void kernel_launch(void* const* d_in, const int* in_sizes, int n_in,
                              void* d_out, int out_size, void* d_ws, size_t ws_size,
                              hipStream_t stream)
{
    const float* p3    = (const float*)d_in[0];
    const float* p4    = (const float*)d_in[1];
    const float* p5    = (const float*)d_in[2];
    const float* boxes = (const float*)d_in[3];
    const float* W3    = (const float*)d_in[4];
    const float* b3    = (const float*)d_in[5];
    const float* W4    = (const float*)d_in[6];
    const float* b4    = (const float*)d_in[7];
    const float* W5    = (const float*)d_in[8];
    const float* b5    = (const float*)d_in[9];
    const float* lng   = (const float*)d_in[10];
    const float* lnb   = (const float*)d_in[11];
    const float* W1    = (const float*)d_in[12];
    const float* b1    = (const float*)d_in[13];
    const float* W2    = (const float*)d_in[14];
    const float* b2    = (const float*)d_in[15];
    const int*   iw    = (const int*)d_in[16];
    const int*   ih    = (const int*)d_in[17];

    const int B = in_sizes[0] / (512 * 128 * 128);   // 8
    const int N = out_size / 256;                    // B*K = 800
    const int K = N / B;                             // 100

    float* G    = (float*)d_ws;                      // N x 3584
    float* P    = G + (size_t)N * 3584;              // N x 3 x 256
    float* WT   = P + (size_t)N * 3 * 256;           // 3584 x 256
    float* W1T  = WT + (size_t)3584 * 256;           // 256 x 256
    float* W2T  = W1T + (size_t)256 * 256;           // 256 x 256
    float* part = W2T + (size_t)256 * 256;           // 7 x N x 256

    float* out = (float*)d_out;

    build_wt_kernel<<<4096, 256, 0, stream>>>(W3, W4, W5, W1, W2, WT, W1T, W2T);
    roi_gather_kernel<<<dim3(N, 3), 256, 0, stream>>>(p3, p4, p5, boxes, b3, b4, b5,
                                                      iw, ih, G, P, K);
    proj_gemm_kernel<<<dim3(N / 8, 7), 256, 0, stream>>>(G, WT, part, N);
    mlp_kernel<<<N / 8, 256, 0, stream>>>(part, P, lng, lnb, W1T, b1, W2T, b2, out, N);
}

// Round 2
// 438.322 us; speedup vs baseline: 1.5514x; 1.5514x over previous
//
#include <hip/hip_runtime.h>
#include <math.h>

#ifndef INT_MAX
#define INT_MAX 0x7fffffff
#endif

// ---------------------------------------------------------------------------
// MultiScaleROIEmbedder: exploit linearity of proj/bilinear/mean:
//   tok_s[n] = (1/36) * ( W_s @ G_s[n] + cnt_n * b_s + P_s[n] )
// G = weighted raw-feature sum over the ROI's dense (row,col) weight grid,
// P = separable positional-encoding sum (analytic sincos), then GEMM + MLP.
// Round 1 -> 2: gather kernel was latency-bound (VGPR=16, 1 load in flight,
// 1.6 TB/s). Now each lane accumulates 4 channels (4 independent load
// streams) with the row loop unrolled x2 -> 8 loads in flight per lane.
// ---------------------------------------------------------------------------

__device__ __forceinline__ float gelu_exact(float x) {
    return 0.5f * x * (1.0f + erff(x * 0.70710678118654752f));
}

// ---- Kernel 0: transpose the projection / MLP weights for coalesced reads --
__global__ __launch_bounds__(256)
void build_wt_kernel(const float* __restrict__ W3, const float* __restrict__ W4,
                     const float* __restrict__ W5, const float* __restrict__ W1,
                     const float* __restrict__ W2,
                     float* __restrict__ WT, float* __restrict__ W1T,
                     float* __restrict__ W2T)
{
    int k = blockIdx.x;      // 0..4095
    int d = threadIdx.x;     // 0..255
    if (k < 512)       WT[(size_t)k * 256 + d]          = W3[(size_t)d * 512  + k];
    else if (k < 1536) WT[(size_t)k * 256 + d]          = W4[(size_t)d * 1024 + (k - 512)];
    else if (k < 3584) WT[(size_t)k * 256 + d]          = W5[(size_t)d * 2048 + (k - 1536)];
    else if (k < 3840) W1T[(size_t)(k - 3584) * 256 + d] = W1[(size_t)d * 256 + (k - 3584)];
    else               W2T[(size_t)(k - 3840) * 256 + d] = W2[(size_t)d * 256 + (k - 3840)];
}

// ---- Kernel 1: per (ROI, scale) weighted feature gather + pos-enc sum ------
__global__ __launch_bounds__(256)
void roi_gather_kernel(const float* __restrict__ p3, const float* __restrict__ p4,
                       const float* __restrict__ p5,
                       const float* __restrict__ boxes,
                       const float* __restrict__ b3, const float* __restrict__ b4,
                       const float* __restrict__ b5,
                       const int* __restrict__ iw_p, const int* __restrict__ ih_p,
                       float* __restrict__ G, float* __restrict__ P,
                       int K)
{
    const int n   = blockIdx.x;   // token index (b*K + k)
    const int s   = blockIdx.y;   // scale 0/1/2
    const int tid = threadIdx.x;

    int C, H, W, koff;
    const float* feat;
    const float* bp;
    if (s == 0)      { C = 512;  H = 128; W = 128; koff = 0;    feat = p3; bp = b3; }
    else if (s == 1) { C = 1024; H = 64;  W = 64;  koff = 512;  feat = p4; bp = b4; }
    else             { C = 2048; H = 32;  W = 32;  koff = 1536; feat = p5; bp = b5; }
    const int HW = H * W;
    const int b  = n / K;

    __shared__ float wy[32];
    __shared__ float wx[48];
    __shared__ int   sh_r0, sh_rs, sh_x0, sh_nc;
    __shared__ float sh_syc, sh_sxc;

    if (tid < 32)                 wy[tid]      = 0.0f;
    if (tid >= 32 && tid < 80)    wx[tid - 32] = 0.0f;
    __syncthreads();

    const float scale = fminf((float)W / ((float)(*iw_p) + 1e-6f),
                              (float)H / ((float)(*ih_p) + 1e-6f));

    if (tid == 0) {
        // y axis: dense row weights (validity folded in)
        float c1 = boxes[(size_t)n * 4 + 1] * scale - 0.5f;
        float c2 = boxes[(size_t)n * 4 + 3] * scale - 0.5f;
        float bs = (c2 - c1) / 3.0f;
        int   yls[6], yhs[6], vv[6];
        float lys[6];
        int r0 = INT_MAX; float cnt = 0.0f;
        #pragma unroll
        for (int i = 0; i < 6; ++i) {
            float off = 0.25f + 0.5f * (float)i;
            float ys  = c1 + bs * off;
            int v = (ys >= -1.0f) && (ys <= (float)H);
            float yc = fmaxf(ys, 0.0f);
            int yl = (int)floorf(yc); if (yl > H - 1) yl = H - 1;
            int yh = yl + 1;          if (yh > H - 1) yh = H - 1;
            float ly = yc - (float)yl;
            yls[i] = yl; yhs[i] = yh; lys[i] = ly; vv[i] = v;
            if (v) { r0 = min(r0, yl); cnt += 1.0f; }
        }
        if (r0 == INT_MAX) r0 = 0;
        int rmax = 0;
        #pragma unroll
        for (int i = 0; i < 6; ++i) if (vv[i]) {
            int a = min(yls[i] - r0, 31);
            int h = min(yhs[i] - r0, 31);
            wy[a] += 1.0f - lys[i];
            wy[h] += lys[i];
            rmax = max(rmax, h);
        }
        sh_r0 = r0; sh_rs = rmax + 1; sh_syc = cnt;
    }
    if (tid == 1) {
        // x axis: dense col weights on a 16-float (64B) aligned window
        float c1 = boxes[(size_t)n * 4 + 0] * scale - 0.5f;
        float c2 = boxes[(size_t)n * 4 + 2] * scale - 0.5f;
        float bs = (c2 - c1) / 3.0f;
        int   xls[6], xhs[6], vv[6];
        float lxs[6];
        int x0r = INT_MAX; float cnt = 0.0f;
        #pragma unroll
        for (int i = 0; i < 6; ++i) {
            float off = 0.25f + 0.5f * (float)i;
            float xs  = c1 + bs * off;
            int v = (xs >= -1.0f) && (xs <= (float)W);
            float xc = fmaxf(xs, 0.0f);
            int xl = (int)floorf(xc); if (xl > W - 1) xl = W - 1;
            int xh = xl + 1;          if (xh > W - 1) xh = W - 1;
            float lx = xc - (float)xl;
            xls[i] = xl; xhs[i] = xh; lxs[i] = lx; vv[i] = v;
            if (v) { x0r = min(x0r, xl); cnt += 1.0f; }
        }
        if (x0r == INT_MAX) x0r = 0;
        int x0 = x0r & ~15;
        int imax = 0;
        #pragma unroll
        for (int i = 0; i < 6; ++i) if (vv[i]) {
            int a = min(xls[i] - x0, 47);
            int h = min(xhs[i] - x0, 47);
            wx[a] += 1.0f - lxs[i];
            wx[h] += lxs[i];
            imax = max(imax, h);
        }
        int nc = imax / 16 + 1;
        int ncmax = (W - x0) >> 4;
        nc = min(nc, ncmax);
        sh_x0 = x0; sh_nc = max(nc, 1); sh_sxc = cnt;
    }
    __syncthreads();

    const int lane = tid & 63;
    const int wv   = tid >> 6;          // wave 0..3
    const int lx   = lane & 15;         // x slot within 64B line
    const int cq   = lane >> 4;         // channel slot within wave (0..3)
    const int r0 = sh_r0, rs = sh_rs, x0 = sh_x0, nc = sh_nc;

    const size_t bbase = (size_t)b * (size_t)C * (size_t)HW;

    // 64 channels per block iteration; each lane owns 4 channels (stride 4)
    for (int it = 0; it < C; it += 64) {
        const int cb = it + (wv << 4) + cq;      // lane's first channel
        const float* fp = feat + bbase + (size_t)cb * HW + (size_t)r0 * W + x0 + lx;

        float acc0 = 0.0f, acc1 = 0.0f, acc2 = 0.0f, acc3 = 0.0f;
        for (int ch = 0; ch < nc; ++ch) {
            const float wxl = wx[(ch << 4) + lx];
            const float* fr = fp + (ch << 4);
            float ra0 = 0.0f, ra1 = 0.0f, ra2 = 0.0f, ra3 = 0.0f;
            int r = 0;
            for (; r + 2 <= rs; r += 2) {
                const float w0 = wy[r], w1 = wy[r + 1];
                const float* a = fr + r * W;
                float v00 = a[0 * HW * 4];
                float v10 = a[1 * HW * 4];
                float v20 = a[2 * HW * 4];
                float v30 = a[3 * HW * 4];
                float v01 = a[0 * HW * 4 + W];
                float v11 = a[1 * HW * 4 + W];
                float v21 = a[2 * HW * 4 + W];
                float v31 = a[3 * HW * 4 + W];
                ra0 = fmaf(w0, v00, ra0); ra0 = fmaf(w1, v01, ra0);
                ra1 = fmaf(w0, v10, ra1); ra1 = fmaf(w1, v11, ra1);
                ra2 = fmaf(w0, v20, ra2); ra2 = fmaf(w1, v21, ra2);
                ra3 = fmaf(w0, v30, ra3); ra3 = fmaf(w1, v31, ra3);
            }
            if (r < rs) {
                const float w0 = wy[r];
                const float* a = fr + r * W;
                ra0 = fmaf(w0, a[0 * HW * 4], ra0);
                ra1 = fmaf(w0, a[1 * HW * 4], ra1);
                ra2 = fmaf(w0, a[2 * HW * 4], ra2);
                ra3 = fmaf(w0, a[3 * HW * 4], ra3);
            }
            acc0 = fmaf(wxl, ra0, acc0);
            acc1 = fmaf(wxl, ra1, acc1);
            acc2 = fmaf(wxl, ra2, acc2);
            acc3 = fmaf(wxl, ra3, acc3);
        }
        // reduce each accumulator over the 16 x-lanes
        #pragma unroll
        for (int o = 8; o; o >>= 1) {
            acc0 += __shfl_xor(acc0, o, 16);
            acc1 += __shfl_xor(acc1, o, 16);
            acc2 += __shfl_xor(acc2, o, 16);
            acc3 += __shfl_xor(acc3, o, 16);
        }
        if (lx == 0) {
            float* g = &G[(size_t)n * 3584 + koff + cb];
            g[0]  = acc0 * (1.0f / 36.0f);
            g[4]  = acc1 * (1.0f / 36.0f);
            g[8]  = acc2 * (1.0f / 36.0f);
            g[12] = acc3 * (1.0f / 36.0f);
        }
    }

    // positional encoding + bias term, folded with count and 1/36
    {
        const int d = tid;
        const float syc = sh_syc, sxc = sh_sxc;
        float val;
        if (d < 128) {
            int   t     = d >> 2;
            float invf  = expf(-(float)t * (logf(10000.0f) / 32.0f));
            float istep = 1.0f / (float)(H - 1);
            float sum = 0.0f;
            for (int r = 0; r < rs; ++r) {
                float w = wy[r];
                float ang = (float)(r0 + r) * istep * invf;
                float sn, cs; sincosf(ang, &sn, &cs);
                sum = fmaf(w, (d & 1) ? cs : sn, sum);
            }
            val = sxc * sum;
        } else {
            int   d2    = d - 128;
            int   t     = d2 >> 2;
            float invf  = expf(-(float)t * (logf(10000.0f) / 32.0f));
            float istep = 1.0f / (float)(W - 1);
            float sum = 0.0f;
            int nx = nc << 4;
            for (int j = 0; j < nx; ++j) {
                float w = wx[j];
                if (w != 0.0f) {
                    float ang = (float)(x0 + j) * istep * invf;
                    float sn, cs; sincosf(ang, &sn, &cs);
                    sum = fmaf(w, (d & 1) ? cs : sn, sum);
                }
            }
            val = syc * sum;
        }
        float cnt = syc * sxc;
        P[((size_t)n * 3 + s) * 256 + d] = (val + cnt * bp[d]) * (1.0f / 36.0f);
    }
}

// ---- Kernel 2: projection GEMM (N x 3584) @ (3584 x 256), K-split by 7 -----
__global__ __launch_bounds__(256)
void proj_gemm_kernel(const float* __restrict__ G, const float* __restrict__ WT,
                      float* __restrict__ part, int N)
{
    const int n0  = blockIdx.x * 8;
    const int kc  = blockIdx.y;          // 0..6, 512 K each
    const int tid = threadIdx.x;         // output dim d

    __shared__ float gl[8][128];
    float acc[8];
    #pragma unroll
    for (int t = 0; t < 8; ++t) acc[t] = 0.0f;

    const int kbase = kc * 512;
    const int lt  = tid >> 5;            // token 0..7 for staging
    const int lc  = (tid & 31) * 4;      // col 0..124

    for (int sub = 0; sub < 4; ++sub) {
        const float4 g4 = *(const float4*)&G[(size_t)(n0 + lt) * 3584 + kbase + sub * 128 + lc];
        *(float4*)&gl[lt][lc] = g4;
        __syncthreads();
        const float* wtp = &WT[(size_t)(kbase + sub * 128) * 256 + tid];
        #pragma unroll 4
        for (int k = 0; k < 128; ++k) {
            float w = wtp[(size_t)k * 256];
            #pragma unroll
            for (int t = 0; t < 8; ++t) acc[t] = fmaf(gl[t][k], w, acc[t]);
        }
        __syncthreads();
    }
    #pragma unroll
    for (int t = 0; t < 8; ++t)
        part[((size_t)kc * N + n0 + t) * 256 + tid] = acc[t];
}

// ---- Kernel 3: reduce partials + P, LayerNorm, Linear-GELU-Linear ----------
__global__ __launch_bounds__(256)
void mlp_kernel(const float* __restrict__ part, const float* __restrict__ P,
                const float* __restrict__ lng, const float* __restrict__ lnb,
                const float* __restrict__ W1T, const float* __restrict__ b1,
                const float* __restrict__ W2T, const float* __restrict__ b2,
                float* __restrict__ out, int N)
{
    const int n0  = blockIdx.x * 8;
    const int tid = threadIdx.x;         // dim d

    __shared__ float tokl[8][257];
    __shared__ float hl[8][257];
    __shared__ float mval[8], rstd[8];

    #pragma unroll
    for (int t = 0; t < 8; ++t) {
        const int n = n0 + t;
        float v = 0.0f;
        #pragma unroll
        for (int c = 0; c < 7; ++c) v += part[((size_t)c * N + n) * 256 + tid];
        #pragma unroll
        for (int s = 0; s < 3; ++s) v += P[((size_t)n * 3 + s) * 256 + tid];
        tokl[t][tid] = v;
    }
    __syncthreads();

    const int wv = tid >> 6, lane = tid & 63;
    for (int t = wv; t < 8; t += 4) {
        float x0 = tokl[t][lane], x1 = tokl[t][lane + 64];
        float x2 = tokl[t][lane + 128], x3 = tokl[t][lane + 192];
        float sm = x0 + x1 + x2 + x3;
        float sq = x0 * x0 + x1 * x1 + x2 * x2 + x3 * x3;
        #pragma unroll
        for (int o = 32; o; o >>= 1) { sm += __shfl_xor(sm, o); sq += __shfl_xor(sq, o); }
        if (lane == 0) {
            float m   = sm * (1.0f / 256.0f);
            float var = sq * (1.0f / 256.0f) - m * m;
            mval[t] = m;
            rstd[t] = rsqrtf(var + 1e-5f);
        }
    }
    __syncthreads();

    const float g = lng[tid], be = lnb[tid];
    #pragma unroll
    for (int t = 0; t < 8; ++t)
        hl[t][tid] = (tokl[t][tid] - mval[t]) * rstd[t] * g + be;
    __syncthreads();

    float acc[8];
    const float bb1 = b1[tid];
    #pragma unroll
    for (int t = 0; t < 8; ++t) acc[t] = bb1;
    for (int k = 0; k < 256; ++k) {
        float w = W1T[(size_t)k * 256 + tid];
        #pragma unroll
        for (int t = 0; t < 8; ++t) acc[t] = fmaf(hl[t][k], w, acc[t]);
    }
    __syncthreads();
    #pragma unroll
    for (int t = 0; t < 8; ++t) tokl[t][tid] = gelu_exact(acc[t]);
    __syncthreads();

    const float bb2 = b2[tid];
    #pragma unroll
    for (int t = 0; t < 8; ++t) acc[t] = bb2;
    for (int k = 0; k < 256; ++k) {
        float w = W2T[(size_t)k * 256 + tid];
        #pragma unroll
        for (int t = 0; t < 8; ++t) acc[t] = fmaf(tokl[t][k], w, acc[t]);
    }
    #pragma unroll
    for (int t = 0; t < 8; ++t)
        out[(size_t)(n0 + t) * 256 + tid] = acc[t];
}

// ---------------------------------------------------------------------------
extern "C" void kernel_launch(void* const* d_in, const int* in_sizes, int n_in,
                              void* d_out, int out_size, void* d_ws, size_t ws_size,
                              hipStream_t stream)
{
    const float* p3    = (const float*)d_in[0];
    const float* p4    = (const float*)d_in[1];
    const float* p5    = (const float*)d_in[2];
    const float* boxes = (const float*)d_in[3];
    const float* W3    = (const float*)d_in[4];
    const float* b3    = (const float*)d_in[5];
    const float* W4    = (const float*)d_in[6];
    const float* b4    = (const float*)d_in[7];
    const float* W5    = (const float*)d_in[8];
    const float* b5    = (const float*)d_in[9];
    const float* lng   = (const float*)d_in[10];
    const float* lnb   = (const float*)d_in[11];
    const float* W1    = (const float*)d_in[12];
    const float* b1    = (const float*)d_in[13];
    const float* W2    = (const float*)d_in[14];
    const float* b2    = (const float*)d_in[15];
    const int*   iw    = (const int*)d_in[16];
    const int*   ih    = (const int*)d_in[17];

    const int B = in_sizes[0] / (512 * 128 * 128);   // 8
    const int N = out_size / 256;                    // B*K = 800
    const int K = N / B;                             // 100

    float* G    = (float*)d_ws;                      // N x 3584
    float* P    = G + (size_t)N * 3584;              // N x 3 x 256
    float* WT   = P + (size_t)N * 3 * 256;           // 3584 x 256
    float* W1T  = WT + (size_t)3584 * 256;           // 256 x 256
    float* W2T  = W1T + (size_t)256 * 256;           // 256 x 256
    float* part = W2T + (size_t)256 * 256;           // 7 x N x 256

    float* out = (float*)d_out;

    build_wt_kernel<<<4096, 256, 0, stream>>>(W3, W4, W5, W1, W2, WT, W1T, W2T);
    roi_gather_kernel<<<dim3(N, 3), 256, 0, stream>>>(p3, p4, p5, boxes, b3, b4, b5,
                                                      iw, ih, G, P, K);
    proj_gemm_kernel<<<dim3(N / 8, 7), 256, 0, stream>>>(G, WT, part, N);
    mlp_kernel<<<N / 8, 256, 0, stream>>>(part, P, lng, lnb, W1T, b1, W2T, b2, out, N);
}

// Round 3
// 269.723 us; speedup vs baseline: 2.5212x; 1.6251x over previous
//
#include <hip/hip_runtime.h>
#include <math.h>

#ifndef INT_MAX
#define INT_MAX 0x7fffffff
#endif

// ---------------------------------------------------------------------------
// MultiScaleROIEmbedder: exploit linearity of proj/bilinear/mean:
//   tok_s[n] = (1/36) * ( W_s @ G_s[n] + cnt_n * b_s + P_s[n] )
// G = weighted raw-feature sum over the ROI's dense (row,col) weight grid,
// P = separable positional-encoding sum (analytic sincos), then GEMM + MLP.
// Round 2 -> 3: gather was tail/latency-bound (2400 imbalanced blocks,
// occupancy 34%, scalar dword loads). Split into 44800 uniform 64-channel
// blocks reading float4; weights precomputed once per (n,s) by setup kernel.
// ---------------------------------------------------------------------------

__device__ __forceinline__ float gelu_exact(float x) {
    return 0.5f * x * (1.0f + erff(x * 0.70710678118654752f));
}

// ---- Kernel 0: transpose the projection / MLP weights for coalesced reads --
__global__ __launch_bounds__(256)
void build_wt_kernel(const float* __restrict__ W3, const float* __restrict__ W4,
                     const float* __restrict__ W5, const float* __restrict__ W1,
                     const float* __restrict__ W2,
                     float* __restrict__ WT, float* __restrict__ W1T,
                     float* __restrict__ W2T)
{
    int k = blockIdx.x;      // 0..4095
    int d = threadIdx.x;     // 0..255
    if (k < 512)       WT[(size_t)k * 256 + d]          = W3[(size_t)d * 512  + k];
    else if (k < 1536) WT[(size_t)k * 256 + d]          = W4[(size_t)d * 1024 + (k - 512)];
    else if (k < 3584) WT[(size_t)k * 256 + d]          = W5[(size_t)d * 2048 + (k - 1536)];
    else if (k < 3840) W1T[(size_t)(k - 3584) * 256 + d] = W1[(size_t)d * 256 + (k - 3584)];
    else               W2T[(size_t)(k - 3840) * 256 + d] = W2[(size_t)d * 256 + (k - 3840)];
}

// ---- Kernel 1a: per (ROI, scale) weight setup + pos-enc --------------------
// Writes a 96-float record per (n,s): [0:32) wy, [32:80) wx,
// 80=r0, 81=rs, 82=x0, 83=nc, 84=syc, 85=sxc. Also writes P.
__global__ __launch_bounds__(256)
void roi_setup_kernel(const float* __restrict__ boxes,
                      const float* __restrict__ b3, const float* __restrict__ b4,
                      const float* __restrict__ b5,
                      const int* __restrict__ iw_p, const int* __restrict__ ih_p,
                      float* __restrict__ WREC, float* __restrict__ P)
{
    const int n   = blockIdx.x;
    const int s   = blockIdx.y;
    const int tid = threadIdx.x;

    int H, W;
    const float* bp;
    if (s == 0)      { H = 128; W = 128; bp = b3; }
    else if (s == 1) { H = 64;  W = 64;  bp = b4; }
    else             { H = 32;  W = 32;  bp = b5; }

    __shared__ float wy[32];
    __shared__ float wx[48];
    __shared__ int   sh_r0, sh_rs, sh_x0, sh_nc;
    __shared__ float sh_syc, sh_sxc;

    if (tid < 32)                 wy[tid]      = 0.0f;
    if (tid >= 32 && tid < 80)    wx[tid - 32] = 0.0f;
    __syncthreads();

    const float scale = fminf((float)W / ((float)(*iw_p) + 1e-6f),
                              (float)H / ((float)(*ih_p) + 1e-6f));

    if (tid == 0) {
        float c1 = boxes[(size_t)n * 4 + 1] * scale - 0.5f;
        float c2 = boxes[(size_t)n * 4 + 3] * scale - 0.5f;
        float bs = (c2 - c1) / 3.0f;
        int   yls[6], yhs[6], vv[6];
        float lys[6];
        int r0 = INT_MAX; float cnt = 0.0f;
        #pragma unroll
        for (int i = 0; i < 6; ++i) {
            float off = 0.25f + 0.5f * (float)i;
            float ys  = c1 + bs * off;
            int v = (ys >= -1.0f) && (ys <= (float)H);
            float yc = fmaxf(ys, 0.0f);
            int yl = (int)floorf(yc); if (yl > H - 1) yl = H - 1;
            int yh = yl + 1;          if (yh > H - 1) yh = H - 1;
            float ly = yc - (float)yl;
            yls[i] = yl; yhs[i] = yh; lys[i] = ly; vv[i] = v;
            if (v) { r0 = min(r0, yl); cnt += 1.0f; }
        }
        if (r0 == INT_MAX) r0 = 0;
        int rmax = 0;
        #pragma unroll
        for (int i = 0; i < 6; ++i) if (vv[i]) {
            int a = min(yls[i] - r0, 31);
            int h = min(yhs[i] - r0, 31);
            wy[a] += 1.0f - lys[i];
            wy[h] += lys[i];
            rmax = max(rmax, h);
        }
        sh_r0 = r0; sh_rs = rmax + 1; sh_syc = cnt;
    }
    if (tid == 1) {
        float c1 = boxes[(size_t)n * 4 + 0] * scale - 0.5f;
        float c2 = boxes[(size_t)n * 4 + 2] * scale - 0.5f;
        float bs = (c2 - c1) / 3.0f;
        int   xls[6], xhs[6], vv[6];
        float lxs[6];
        int x0r = INT_MAX; float cnt = 0.0f;
        #pragma unroll
        for (int i = 0; i < 6; ++i) {
            float off = 0.25f + 0.5f * (float)i;
            float xs  = c1 + bs * off;
            int v = (xs >= -1.0f) && (xs <= (float)W);
            float xc = fmaxf(xs, 0.0f);
            int xl = (int)floorf(xc); if (xl > W - 1) xl = W - 1;
            int xh = xl + 1;          if (xh > W - 1) xh = W - 1;
            float lx = xc - (float)xl;
            xls[i] = xl; xhs[i] = xh; lxs[i] = lx; vv[i] = v;
            if (v) { x0r = min(x0r, xl); cnt += 1.0f; }
        }
        if (x0r == INT_MAX) x0r = 0;
        int x0 = x0r & ~15;
        int imax = 0;
        #pragma unroll
        for (int i = 0; i < 6; ++i) if (vv[i]) {
            int a = min(xls[i] - x0, 47);
            int h = min(xhs[i] - x0, 47);
            wx[a] += 1.0f - lxs[i];
            wx[h] += lxs[i];
            imax = max(imax, h);
        }
        int nc = imax / 16 + 1;
        int ncmax = (W - x0) >> 4;
        nc = min(nc, ncmax);
        sh_x0 = x0; sh_nc = max(nc, 1); sh_sxc = cnt;
    }
    __syncthreads();

    const int r0 = sh_r0, rs = sh_rs, x0 = sh_x0, nc = sh_nc;

    // write weight record
    float* rec = &WREC[(size_t)(n * 3 + s) * 96];
    if (tid < 32)                 rec[tid]      = wy[tid];
    else if (tid < 80)            rec[tid]      = wx[tid - 32];
    else if (tid == 80)           rec[80]       = (float)r0;
    else if (tid == 81)           rec[81]       = (float)rs;
    else if (tid == 82)           rec[82]       = (float)x0;
    else if (tid == 83)           rec[83]       = (float)nc;
    else if (tid == 84)           rec[84]       = sh_syc;
    else if (tid == 85)           rec[85]       = sh_sxc;

    // positional encoding + bias term, folded with count and 1/36
    {
        const int d = tid;
        const float syc = sh_syc, sxc = sh_sxc;
        float val;
        if (d < 128) {
            int   t     = d >> 2;
            float invf  = expf(-(float)t * (logf(10000.0f) / 32.0f));
            float istep = 1.0f / (float)(H - 1);
            float sum = 0.0f;
            for (int r = 0; r < rs; ++r) {
                float w = wy[r];
                float ang = (float)(r0 + r) * istep * invf;
                float sn, cs; sincosf(ang, &sn, &cs);
                sum = fmaf(w, (d & 1) ? cs : sn, sum);
            }
            val = sxc * sum;
        } else {
            int   d2    = d - 128;
            int   t     = d2 >> 2;
            float invf  = expf(-(float)t * (logf(10000.0f) / 32.0f));
            float istep = 1.0f / (float)(W - 1);
            float sum = 0.0f;
            int nx = nc << 4;
            for (int j = 0; j < nx; ++j) {
                float w = wx[j];
                if (w != 0.0f) {
                    float ang = (float)(x0 + j) * istep * invf;
                    float sn, cs; sincosf(ang, &sn, &cs);
                    sum = fmaf(w, (d & 1) ? cs : sn, sum);
                }
            }
            val = syc * sum;
        }
        float cnt = syc * sxc;
        P[((size_t)n * 3 + s) * 256 + d] = (val + cnt * bp[d]) * (1.0f / 36.0f);
    }
}

// ---- Kernel 1b: weighted feature gather, 64 channels per block -------------
// grid = (56, N): chunk-id x token. Each lane owns 1 channel's 4-float slot;
// 4 lanes per channel, float4 loads, rows unrolled x4.
__global__ __launch_bounds__(256)
void roi_gather_kernel(const float* __restrict__ p3, const float* __restrict__ p4,
                       const float* __restrict__ p5,
                       const float* __restrict__ WREC,
                       float* __restrict__ G, int K)
{
    const int yc  = blockIdx.x;   // 0..55
    const int n   = blockIdx.y;   // token
    const int tid = threadIdx.x;

    int s, chunk;
    if (yc < 8)       { s = 0; chunk = yc; }
    else if (yc < 24) { s = 1; chunk = yc - 8; }
    else              { s = 2; chunk = yc - 24; }

    int C, H, W, koff;
    const float* feat;
    if (s == 0)      { C = 512;  H = 128; W = 128; koff = 0;    feat = p3; }
    else if (s == 1) { C = 1024; H = 64;  W = 64;  koff = 512;  feat = p4; }
    else             { C = 2048; H = 32;  W = 32;  koff = 1536; feat = p5; }
    const int HW = H * W;
    const int b  = n / K;

    __shared__ float sh[96];
    if (tid < 96) sh[tid] = WREC[(size_t)(n * 3 + s) * 96 + tid];
    __syncthreads();

    const int r0 = (int)sh[80];
    const int rs = (int)sh[81];
    const int x0 = (int)sh[82];
    const int nc = (int)sh[83];

    const int c    = chunk * 64 + (tid >> 2);   // this lane's channel
    const int slot = tid & 3;                   // 4-float slot in the 16-wide line

    const float* fp = feat + (size_t)b * C * HW + (size_t)c * HW
                    + (size_t)r0 * W + x0 + slot * 4;

    float acc = 0.0f;
    for (int ch = 0; ch < nc; ++ch) {
        const float4 wxv = *(const float4*)&sh[32 + (ch << 4) + slot * 4];
        const float* a = fp + (ch << 4);
        float4 ra = make_float4(0.f, 0.f, 0.f, 0.f);
        int r = 0;
        for (; r + 4 <= rs; r += 4) {
            const float4 v0 = *(const float4*)(a + (size_t)(r + 0) * W);
            const float4 v1 = *(const float4*)(a + (size_t)(r + 1) * W);
            const float4 v2 = *(const float4*)(a + (size_t)(r + 2) * W);
            const float4 v3 = *(const float4*)(a + (size_t)(r + 3) * W);
            const float w0 = sh[r], w1 = sh[r + 1], w2 = sh[r + 2], w3 = sh[r + 3];
            ra.x = fmaf(w0, v0.x, ra.x); ra.y = fmaf(w0, v0.y, ra.y);
            ra.z = fmaf(w0, v0.z, ra.z); ra.w = fmaf(w0, v0.w, ra.w);
            ra.x = fmaf(w1, v1.x, ra.x); ra.y = fmaf(w1, v1.y, ra.y);
            ra.z = fmaf(w1, v1.z, ra.z); ra.w = fmaf(w1, v1.w, ra.w);
            ra.x = fmaf(w2, v2.x, ra.x); ra.y = fmaf(w2, v2.y, ra.y);
            ra.z = fmaf(w2, v2.z, ra.z); ra.w = fmaf(w2, v2.w, ra.w);
            ra.x = fmaf(w3, v3.x, ra.x); ra.y = fmaf(w3, v3.y, ra.y);
            ra.z = fmaf(w3, v3.z, ra.z); ra.w = fmaf(w3, v3.w, ra.w);
        }
        for (; r < rs; ++r) {
            const float4 v = *(const float4*)(a + (size_t)r * W);
            const float w = sh[r];
            ra.x = fmaf(w, v.x, ra.x); ra.y = fmaf(w, v.y, ra.y);
            ra.z = fmaf(w, v.z, ra.z); ra.w = fmaf(w, v.w, ra.w);
        }
        float d = ra.x * wxv.x + ra.y * wxv.y + ra.z * wxv.z + ra.w * wxv.w;
        acc += d;
    }
    // reduce over the 4 slots of this channel
    acc += __shfl_xor(acc, 1, 4);
    acc += __shfl_xor(acc, 2, 4);
    if (slot == 0)
        G[(size_t)n * 3584 + koff + c] = acc * (1.0f / 36.0f);
}

// ---- Kernel 2: projection GEMM (N x 3584) @ (3584 x 256), K-split by 7 -----
__global__ __launch_bounds__(256)
void proj_gemm_kernel(const float* __restrict__ G, const float* __restrict__ WT,
                      float* __restrict__ part, int N)
{
    const int n0  = blockIdx.x * 8;
    const int kc  = blockIdx.y;          // 0..6, 512 K each
    const int tid = threadIdx.x;         // output dim d

    __shared__ float gl[8][128];
    float acc[8];
    #pragma unroll
    for (int t = 0; t < 8; ++t) acc[t] = 0.0f;

    const int kbase = kc * 512;
    const int lt  = tid >> 5;            // token 0..7 for staging
    const int lc  = (tid & 31) * 4;      // col 0..124

    for (int sub = 0; sub < 4; ++sub) {
        const float4 g4 = *(const float4*)&G[(size_t)(n0 + lt) * 3584 + kbase + sub * 128 + lc];
        *(float4*)&gl[lt][lc] = g4;
        __syncthreads();
        const float* wtp = &WT[(size_t)(kbase + sub * 128) * 256 + tid];
        #pragma unroll 4
        for (int k = 0; k < 128; ++k) {
            float w = wtp[(size_t)k * 256];
            #pragma unroll
            for (int t = 0; t < 8; ++t) acc[t] = fmaf(gl[t][k], w, acc[t]);
        }
        __syncthreads();
    }
    #pragma unroll
    for (int t = 0; t < 8; ++t)
        part[((size_t)kc * N + n0 + t) * 256 + tid] = acc[t];
}

// ---- Kernel 3: reduce partials + P, LayerNorm, Linear-GELU-Linear ----------
__global__ __launch_bounds__(256)
void mlp_kernel(const float* __restrict__ part, const float* __restrict__ P,
                const float* __restrict__ lng, const float* __restrict__ lnb,
                const float* __restrict__ W1T, const float* __restrict__ b1,
                const float* __restrict__ W2T, const float* __restrict__ b2,
                float* __restrict__ out, int N)
{
    const int n0  = blockIdx.x * 8;
    const int tid = threadIdx.x;         // dim d

    __shared__ float tokl[8][257];
    __shared__ float hl[8][257];
    __shared__ float mval[8], rstd[8];

    #pragma unroll
    for (int t = 0; t < 8; ++t) {
        const int n = n0 + t;
        float v = 0.0f;
        #pragma unroll
        for (int c = 0; c < 7; ++c) v += part[((size_t)c * N + n) * 256 + tid];
        #pragma unroll
        for (int s = 0; s < 3; ++s) v += P[((size_t)n * 3 + s) * 256 + tid];
        tokl[t][tid] = v;
    }
    __syncthreads();

    const int wv = tid >> 6, lane = tid & 63;
    for (int t = wv; t < 8; t += 4) {
        float x0 = tokl[t][lane], x1 = tokl[t][lane + 64];
        float x2 = tokl[t][lane + 128], x3 = tokl[t][lane + 192];
        float sm = x0 + x1 + x2 + x3;
        float sq = x0 * x0 + x1 * x1 + x2 * x2 + x3 * x3;
        #pragma unroll
        for (int o = 32; o; o >>= 1) { sm += __shfl_xor(sm, o); sq += __shfl_xor(sq, o); }
        if (lane == 0) {
            float m   = sm * (1.0f / 256.0f);
            float var = sq * (1.0f / 256.0f) - m * m;
            mval[t] = m;
            rstd[t] = rsqrtf(var + 1e-5f);
        }
    }
    __syncthreads();

    const float g = lng[tid], be = lnb[tid];
    #pragma unroll
    for (int t = 0; t < 8; ++t)
        hl[t][tid] = (tokl[t][tid] - mval[t]) * rstd[t] * g + be;
    __syncthreads();

    float acc[8];
    const float bb1 = b1[tid];
    #pragma unroll
    for (int t = 0; t < 8; ++t) acc[t] = bb1;
    for (int k = 0; k < 256; ++k) {
        float w = W1T[(size_t)k * 256 + tid];
        #pragma unroll
        for (int t = 0; t < 8; ++t) acc[t] = fmaf(hl[t][k], w, acc[t]);
    }
    __syncthreads();
    #pragma unroll
    for (int t = 0; t < 8; ++t) tokl[t][tid] = gelu_exact(acc[t]);
    __syncthreads();

    const float bb2 = b2[tid];
    #pragma unroll
    for (int t = 0; t < 8; ++t) acc[t] = bb2;
    for (int k = 0; k < 256; ++k) {
        float w = W2T[(size_t)k * 256 + tid];
        #pragma unroll
        for (int t = 0; t < 8; ++t) acc[t] = fmaf(tokl[t][k], w, acc[t]);
    }
    #pragma unroll
    for (int t = 0; t < 8; ++t)
        out[(size_t)(n0 + t) * 256 + tid] = acc[t];
}

// ---------------------------------------------------------------------------
extern "C" void kernel_launch(void* const* d_in, const int* in_sizes, int n_in,
                              void* d_out, int out_size, void* d_ws, size_t ws_size,
                              hipStream_t stream)
{
    const float* p3    = (const float*)d_in[0];
    const float* p4    = (const float*)d_in[1];
    const float* p5    = (const float*)d_in[2];
    const float* boxes = (const float*)d_in[3];
    const float* W3    = (const float*)d_in[4];
    const float* b3    = (const float*)d_in[5];
    const float* W4    = (const float*)d_in[6];
    const float* b4    = (const float*)d_in[7];
    const float* W5    = (const float*)d_in[8];
    const float* b5    = (const float*)d_in[9];
    const float* lng   = (const float*)d_in[10];
    const float* lnb   = (const float*)d_in[11];
    const float* W1    = (const float*)d_in[12];
    const float* b1    = (const float*)d_in[13];
    const float* W2    = (const float*)d_in[14];
    const float* b2    = (const float*)d_in[15];
    const int*   iw    = (const int*)d_in[16];
    const int*   ih    = (const int*)d_in[17];

    const int B = in_sizes[0] / (512 * 128 * 128);   // 8
    const int N = out_size / 256;                    // B*K = 800
    const int K = N / B;                             // 100

    float* G    = (float*)d_ws;                      // N x 3584
    float* P    = G + (size_t)N * 3584;              // N x 3 x 256
    float* WT   = P + (size_t)N * 3 * 256;           // 3584 x 256
    float* W1T  = WT + (size_t)3584 * 256;           // 256 x 256
    float* W2T  = W1T + (size_t)256 * 256;           // 256 x 256
    float* part = W2T + (size_t)256 * 256;           // 7 x N x 256
    float* WREC = part + (size_t)7 * N * 256;        // N x 3 x 96

    float* out = (float*)d_out;

    build_wt_kernel<<<4096, 256, 0, stream>>>(W3, W4, W5, W1, W2, WT, W1T, W2T);
    roi_setup_kernel<<<dim3(N, 3), 256, 0, stream>>>(boxes, b3, b4, b5, iw, ih, WREC, P);
    roi_gather_kernel<<<dim3(56, N), 256, 0, stream>>>(p3, p4, p5, WREC, G, K);
    proj_gemm_kernel<<<dim3(N / 8, 7), 256, 0, stream>>>(G, WT, part, N);
    mlp_kernel<<<N / 8, 256, 0, stream>>>(part, P, lng, lnb, W1T, b1, W2T, b2, out, N);
}